// Round 4
// baseline (352.648 us; speedup 1.0000x reference)
//
#include <hip/hip_runtime.h>
#include <math.h>

// Problem constants
#define BS 4
#define LQ 1024
#define EMB 256
#define NH 8
#define NL 4
#define NP 16
#define HD 32
#define LV 5440   // 64*64 + 32*32 + 16*16 + 8*8
#define KDIM 256  // all GEMMs have K = 256

typedef __attribute__((ext_vector_type(8))) short short8;  // 8 bf16 = 4 VGPRs
typedef __attribute__((ext_vector_type(4))) float f32x4;

__device__ inline unsigned short f2bf(float f) {
    unsigned u = __builtin_bit_cast(unsigned, f);
    u += 0x7fff + ((u >> 16) & 1);   // round-to-nearest-even
    return (unsigned short)(u >> 16);
}

// ---- all 4 weights [K=256][N] fp32 -> Wt_all[2048][256] bf16 (transpose+convert)
// col map: 0..255 W_value | 256..1279 W_off | 1280..1791 W_attn | 1792..2047 W_out
__global__ __launch_bounds__(256) void convT_all(const float* __restrict__ Wv,
                                                 const float* __restrict__ Wo,
                                                 const float* __restrict__ Wa,
                                                 const float* __restrict__ Wu,
                                                 unsigned short* __restrict__ Wt) {
    __shared__ float tile[32][33];
    const int n0 = blockIdx.x * 32, k0 = blockIdx.y * 32;
    const float* src; int N, nloc;
    if (n0 < 256)       { src = Wv; N = 256;  nloc = n0; }
    else if (n0 < 1280) { src = Wo; N = 1024; nloc = n0 - 256; }
    else if (n0 < 1792) { src = Wa; N = 512;  nloc = n0 - 1280; }
    else                { src = Wu; N = 256;  nloc = n0 - 1792; }
    const int tx = threadIdx.x & 31, ty = threadIdx.x >> 5;  // ty 0..7
#pragma unroll
    for (int i = 0; i < 32; i += 8)
        tile[ty + i][tx] = src[(size_t)(k0 + ty + i) * N + nloc + tx];
    __syncthreads();
#pragma unroll
    for (int i = 0; i < 32; i += 8)
        Wt[(size_t)(n0 + ty + i) * KDIM + k0 + tx] = f2bf(tile[tx][ty + i]);
}

// ---------------- bf16 MFMA GEMM, 128x128 tile (m97 structure) -------------------
// 256 threads = 4 waves in 2x2; each wave computes 64x64 via 4x4 frags of
// 16x16x32. BK=32, K=256 fixed. B staged via global_load_lds width 16.
// A: fp32 (converted in VGPRs during staging) or bf16 (glds).
// MODE 0: fp32 C = acc + bias[c]
// MODE 1: fused qkv epilogue (N=1536): cols <1024 -> sampling locations with
//         reference-point polynomial (fp32 C); cols >=1024 -> attn logits with
//         FUSED SOFTMAX over the 64 logits of each (row, head) -> fp32 C2.
// MODE 2: bf16 C = f2bf(acc + bias[c])
template <bool A_FP32, int MODE>
__global__ __launch_bounds__(256) void gemm128(const void* __restrict__ Aptr,
                                               const unsigned short* __restrict__ Bt,
                                               const float* __restrict__ bias,
                                               const float* __restrict__ bias2,
                                               const float* __restrict__ refp,
                                               void* __restrict__ Cv,
                                               float* __restrict__ C2,
                                               int N) {
    __shared__ short As[128 * 32];
    __shared__ short Bs[128 * 32];
    const int t = threadIdx.x;
    const int lane = t & 63, w = t >> 6;
    const int quad = lane >> 4, l16 = lane & 15;
    const int wr = w >> 1, wc = w & 1;
    const int row0 = blockIdx.y * 128, col0 = blockIdx.x * 128;

    f32x4 acc[4][4] = {};

    // B staging: chunk covers 16B: row t>>2, k-offset (t&3)*8 elems
    const int bro = t >> 2, bko = (t & 3) * 8;
    const unsigned short* bsrc0 = Bt + (size_t)(col0 + bro) * KDIM + bko;
    const unsigned short* bsrc1 = bsrc0 + (size_t)64 * KDIM;
    short* const bdst0 = Bs + (size_t)(w * 64) * 8;          // + lane*16B by HW
    short* const bdst1 = Bs + (size_t)(256 + w * 64) * 8;

    // A staging (fp32 path): thread t covers 16 floats: row t>>1, k-half (t&1)*16
    const int ar = t >> 1, akq = (t & 1) * 16;
    const float* afsrc = (const float*)Aptr + (size_t)(row0 + ar) * KDIM + akq;
    short* const adst = As + ar * 32 + akq;
    // A staging (bf16 path): same pattern as B
    const unsigned short* absrc0 = (const unsigned short*)Aptr + (size_t)(row0 + bro) * KDIM + bko;
    const unsigned short* absrc1 = absrc0 + (size_t)64 * KDIM;
    short* const adst0 = As + (size_t)(w * 64) * 8;
    short* const adst1 = As + (size_t)(256 + w * 64) * 8;

    for (int kt = 0; kt < KDIM / 32; ++kt) {
        __syncthreads();
        __builtin_amdgcn_global_load_lds(
            (const __attribute__((address_space(1))) void*)(bsrc0 + kt * 32),
            (__attribute__((address_space(3))) void*)bdst0, 16, 0, 0);
        __builtin_amdgcn_global_load_lds(
            (const __attribute__((address_space(1))) void*)(bsrc1 + kt * 32),
            (__attribute__((address_space(3))) void*)bdst1, 16, 0, 0);
        if (A_FP32) {
            const float* s = afsrc + kt * 32;
            const float4 f0 = *(const float4*)(s);
            const float4 f1 = *(const float4*)(s + 4);
            const float4 f2 = *(const float4*)(s + 8);
            const float4 f3 = *(const float4*)(s + 12);
            short8 h0, h1;
            h0[0] = (short)f2bf(f0.x); h0[1] = (short)f2bf(f0.y);
            h0[2] = (short)f2bf(f0.z); h0[3] = (short)f2bf(f0.w);
            h0[4] = (short)f2bf(f1.x); h0[5] = (short)f2bf(f1.y);
            h0[6] = (short)f2bf(f1.z); h0[7] = (short)f2bf(f1.w);
            h1[0] = (short)f2bf(f2.x); h1[1] = (short)f2bf(f2.y);
            h1[2] = (short)f2bf(f2.z); h1[3] = (short)f2bf(f2.w);
            h1[4] = (short)f2bf(f3.x); h1[5] = (short)f2bf(f3.y);
            h1[6] = (short)f2bf(f3.z); h1[7] = (short)f2bf(f3.w);
            *(short8*)(adst)     = h0;
            *(short8*)(adst + 8) = h1;
        } else {
            __builtin_amdgcn_global_load_lds(
                (const __attribute__((address_space(1))) void*)(absrc0 + kt * 32),
                (__attribute__((address_space(3))) void*)adst0, 16, 0, 0);
            __builtin_amdgcn_global_load_lds(
                (const __attribute__((address_space(1))) void*)(absrc1 + kt * 32),
                (__attribute__((address_space(3))) void*)adst1, 16, 0, 0);
        }
        __syncthreads();

        short8 af[4], bf[4];
#pragma unroll
        for (int mi = 0; mi < 4; ++mi)
            af[mi] = *(const short8*)&As[(wr * 64 + mi * 16 + l16) * 32 + quad * 8];
#pragma unroll
        for (int ni = 0; ni < 4; ++ni)
            bf[ni] = *(const short8*)&Bs[(wc * 64 + ni * 16 + l16) * 32 + quad * 8];
#pragma unroll
        for (int mi = 0; mi < 4; ++mi)
#pragma unroll
            for (int ni = 0; ni < 4; ++ni)
                acc[mi][ni] = __builtin_amdgcn_mfma_f32_16x16x32_bf16(af[mi], bf[ni],
                                                                      acc[mi][ni], 0, 0, 0);
    }

    // C/D layout: col = lane&15, row = quad*4 + reg  [m89-verified, R2/R3-verified]
    if (MODE == 0 || MODE == 2) {
#pragma unroll
        for (int ni = 0; ni < 4; ++ni) {
            const int c = col0 + wc * 64 + ni * 16 + l16;
            const float bv = bias[c];
#pragma unroll
            for (int mi = 0; mi < 4; ++mi) {
                const int r0 = row0 + wr * 64 + mi * 16 + quad * 4;
#pragma unroll
                for (int rr = 0; rr < 4; ++rr) {
                    const float o = acc[mi][ni][rr] + bv;
                    if (MODE == 0) ((float*)Cv)[(size_t)(r0 + rr) * N + c] = o;
                    else ((unsigned short*)Cv)[(size_t)(r0 + rr) * N + c] = f2bf(o);
                }
            }
        }
    } else {
        const bool is_off = (col0 < 1024);   // block-uniform (1024 % 128 == 0)
        if (is_off) {
            float* C = (float*)Cv;
#pragma unroll
            for (int ni = 0; ni < 4; ++ni) {
                const int cg = col0 + wc * 64 + ni * 16 + l16;
                // cg = h*128 + l*32 + p*2 + xy
                const int xy = cg & 1, p = (cg >> 1) & 15, l = (cg >> 5) & 3;
                const float lam = (float)p * (1.0f / 15.0f);
                const float l2 = lam * lam, l3 = l2 * lam;
                const float rW = (l == 0) ? 0.015625f : (l == 1) ? 0.03125f
                                : (l == 2) ? 0.0625f : 0.125f;
                const float bv = bias[cg];
#pragma unroll
                for (int mi = 0; mi < 4; ++mi) {
                    const int r0 = row0 + wr * 64 + mi * 16 + quad * 4;
#pragma unroll
                    for (int rr = 0; rr < 4; ++rr) {
                        const int r = r0 + rr;
                        const float4 rp = *(const float4*)(refp + (size_t)r * 8 + xy * 4);
                        const float poly = rp.x * l3 + rp.y * l2 + rp.z * lam + rp.w;
                        C[(size_t)r * 1024 + cg] = poly + (acc[mi][ni][rr] + bv) * rW;
                    }
                }
            }
        } else {
            // fused softmax: this wave holds one head's 64 logits (ni*16+l16)
            // for 64 rows. Reduce over ni (in-reg) x l16 (shfl_xor 1,2,4,8).
            const int cabase = col0 - 1024 + wc * 64;   // multiple of 64
            float bv[4];
#pragma unroll
            for (int ni = 0; ni < 4; ++ni) bv[ni] = bias2[cabase + ni * 16 + l16];
#pragma unroll
            for (int mi = 0; mi < 4; ++mi) {
                const int r0 = row0 + wr * 64 + mi * 16 + quad * 4;
#pragma unroll
                for (int rr = 0; rr < 4; ++rr) {
                    float v0 = acc[mi][0][rr] + bv[0];
                    float v1 = acc[mi][1][rr] + bv[1];
                    float v2 = acc[mi][2][rr] + bv[2];
                    float v3 = acc[mi][3][rr] + bv[3];
                    float mx = fmaxf(fmaxf(v0, v1), fmaxf(v2, v3));
#pragma unroll
                    for (int mk = 1; mk < 16; mk <<= 1) mx = fmaxf(mx, __shfl_xor(mx, mk));
                    v0 = __expf(v0 - mx); v1 = __expf(v1 - mx);
                    v2 = __expf(v2 - mx); v3 = __expf(v3 - mx);
                    float s = v0 + v1 + v2 + v3;
#pragma unroll
                    for (int mk = 1; mk < 16; mk <<= 1) s += __shfl_xor(s, mk);
                    const float inv = 1.0f / s;
                    const size_t rb = (size_t)(r0 + rr) * 512 + cabase + l16;
                    C2[rb]      = v0 * inv;
                    C2[rb + 16] = v1 * inv;
                    C2[rb + 32] = v2 * inv;
                    C2[rb + 48] = v3 * inv;
                }
            }
        }
    }
}

// ---------------- bilinear sampling + attention weighting (bf16 v) ---------------
// 16 lanes per (b,q,h): lane = (lvl 0..3) x (channel-octet 0..3); each lane
// loads 8 bf16 channels (16B) per corner -> full 64B head-row per 4 lanes.
// Scalar point math redundancy = 4x. Cross-level reduce via shfl_xor(4,8).
__global__ __launch_bounds__(256) void sample_kernel(const unsigned short* __restrict__ v,
                                                     const float* __restrict__ loc,
                                                     const float* __restrict__ attn,
                                                     unsigned short* __restrict__ interm) {
    const int t = threadIdx.x;
    const int g = blockIdx.x * 16 + (t >> 4);   // (b*1024+q)*8 + h
    const int l16 = t & 15;
    const int lvl = l16 >> 2;                   // level 0..3
    const int cq  = l16 & 3;                    // channel octet
    const int h = g & 7, bq = g >> 3, b = bq >> 10;

    const int W = 64 >> lvl;
    const float Wf = (float)W;
    const int sh = 6 - lvl;
    const int start = (lvl == 0) ? 0 : (lvl == 1) ? 4096 : (lvl == 2) ? 5120 : 5376;

    const float* lp = loc  + (size_t)g * 128 + lvl * 32;   // this level's 16 pts
    const float* ap = attn + (size_t)g * 64  + lvl * 16;
    const unsigned short* vl = v + ((size_t)b * LV + start) * EMB + h * HD + cq * 8;

    float acc[8] = {};

    auto cadd = [&](uint4 q, float wgt) {
        const unsigned dw[4] = {q.x, q.y, q.z, q.w};
#pragma unroll
        for (int k = 0; k < 4; ++k) {
            const float lo = __builtin_bit_cast(float, dw[k] << 16);
            const float hi = __builtin_bit_cast(float, dw[k] & 0xffff0000u);
            acc[2 * k]     = fmaf(wgt, lo, acc[2 * k]);
            acc[2 * k + 1] = fmaf(wgt, hi, acc[2 * k + 1]);
        }
    };

    auto point = [&](float lx, float ly, float wt) {
        const float x = lx * Wf - 0.5f, y = ly * Wf - 0.5f;
        const float x0f = floorf(x), y0f = floorf(y);
        const float wx = x - x0f, wy = y - y0f;
        const int x0 = (int)x0f, y0 = (int)y0f;
        const int x1 = x0 + 1, y1 = y0 + 1;
        const float iwx = 1.f - wx, iwy = 1.f - wy;
        float w00 = iwx * iwy * wt, w10 = wx * iwy * wt;
        float w01 = iwx * wy * wt,  w11 = wx * wy * wt;
        const bool vx0 = (unsigned)x0 < (unsigned)W;
        const bool vx1 = (unsigned)x1 < (unsigned)W;
        const bool vy0 = (unsigned)y0 < (unsigned)W;
        const bool vy1 = (unsigned)y1 < (unsigned)W;
        w00 = (vx0 & vy0) ? w00 : 0.f;
        w10 = (vx1 & vy0) ? w10 : 0.f;
        w01 = (vx0 & vy1) ? w01 : 0.f;
        w11 = (vx1 & vy1) ? w11 : 0.f;
        const int cx0 = min(max(x0, 0), W - 1);
        const int cx1 = min(max(x1, 0), W - 1);
        const int cy0 = min(max(y0, 0), W - 1);
        const int cy1 = min(max(y1, 0), W - 1);
        const uint4 g00 = *(const uint4*)(vl + (size_t)((cy0 << sh) + cx0) * EMB);
        const uint4 g10 = *(const uint4*)(vl + (size_t)((cy0 << sh) + cx1) * EMB);
        const uint4 g01 = *(const uint4*)(vl + (size_t)((cy1 << sh) + cx0) * EMB);
        const uint4 g11 = *(const uint4*)(vl + (size_t)((cy1 << sh) + cx1) * EMB);
        cadd(g00, w00); cadd(g10, w10); cadd(g01, w01); cadd(g11, w11);
    };

#pragma unroll
    for (int p4 = 0; p4 < 16; p4 += 4) {
        const float4 la = *(const float4*)(lp + 2 * p4);
        const float4 lb = *(const float4*)(lp + 2 * p4 + 4);
        const float4 wv = *(const float4*)(ap + p4);
        point(la.x, la.y, wv.x); point(la.z, la.w, wv.y);
        point(lb.x, lb.y, wv.z); point(lb.z, lb.w, wv.w);
    }

    // reduce across the 4 level-quads (lane bits 2,3)
#pragma unroll
    for (int m = 4; m <= 8; m <<= 1)
#pragma unroll
        for (int k = 0; k < 8; ++k) acc[k] += __shfl_xor(acc[k], m);

    if (lvl == 0) {
        unsigned short o[8];
#pragma unroll
        for (int k = 0; k < 8; ++k) o[k] = f2bf(acc[k]);
        *(uint4*)(interm + (size_t)bq * EMB + h * HD + cq * 8) = *(const uint4*)o;
    }
}

// ---------------- host launch ----------------------------------------------------
extern "C" void kernel_launch(void* const* d_in, const int* in_sizes, int n_in,
                              void* d_out, int out_size, void* d_ws, size_t ws_size,
                              hipStream_t stream) {
    const float* query   = (const float*)d_in[0];
    const float* refp    = (const float*)d_in[1];
    const float* value   = (const float*)d_in[2];
    const float* W_value = (const float*)d_in[3];
    const float* b_value = (const float*)d_in[4];
    const float* W_off   = (const float*)d_in[5];
    const float* b_off   = (const float*)d_in[6];
    const float* W_attn  = (const float*)d_in[7];
    const float* b_attn  = (const float*)d_in[8];
    const float* W_out   = (const float*)d_in[9];
    const float* b_out   = (const float*)d_in[10];

    float* out      = (float*)d_out;            // [4,1024,256]
    float* loc_out  = out + 1048576;            // [4,1024,8,4,16,2]
    float* attn_out = out + 5242880;            // [4,1024,8,4,16]

    // workspace layout (14,286,848 B)
    char* ws = (char*)d_ws;
    unsigned short* v_proj = (unsigned short*)ws;                 // 11,141,120 B (bf16)
    unsigned short* interm = (unsigned short*)(ws + 11141120);    //  2,097,152 B
    unsigned short* Wt_all = (unsigned short*)(ws + 13238272);    //  1,048,576 B

    const dim3 blk(256);

    // transpose+convert all weights -> Wt_all[2048][256] bf16
    convT_all<<<dim3(2048 / 32, 8), blk, 0, stream>>>(W_value, W_off, W_attn, W_out, Wt_all);

    // v = value @ W_value + b  -> bf16 v_proj
    gemm128<true, 2><<<dim3(2, 170), blk, 0, stream>>>(
        value, Wt_all, b_value, nullptr, nullptr, v_proj, nullptr, 256);

    // fused offsets+attn GEMM (N=1536): loc-poly epilogue + fused softmax
    gemm128<true, 1><<<dim3(12, 32), blk, 0, stream>>>(
        query, Wt_all + (size_t)256 * KDIM, b_off, b_attn, refp, loc_out, attn_out, 1536);

    // bilinear gather + attention weighting (bf16 v)
    sample_kernel<<<(BS * LQ * NH) / 16, blk, 0, stream>>>(v_proj, loc_out, attn_out, interm);

    // output = interm @ W_out + b  (A bf16, fp32 out)
    gemm128<false, 0><<<dim3(2, 32), blk, 0, stream>>>(
        interm, Wt_all + (size_t)1792 * KDIM, b_out, nullptr, nullptr, out, nullptr, 256);
}

// Round 5
// 176.994 us; speedup vs baseline: 1.9924x; 1.9924x over previous
//
#include <hip/hip_runtime.h>
#include <math.h>

// Problem constants
#define BS 4
#define LQ 1024
#define EMB 256
#define NH 8
#define NL 4
#define NP 16
#define HD 32
#define LV 5440   // 64*64 + 32*32 + 16*16 + 8*8
#define KDIM 256  // all GEMMs have K = 256

typedef __attribute__((ext_vector_type(8))) short short8;  // 8 bf16 = 4 VGPRs
typedef __attribute__((ext_vector_type(4))) float f32x4;

__device__ inline unsigned short f2bf(float f) {
    unsigned u = __builtin_bit_cast(unsigned, f);
    u += 0x7fff + ((u >> 16) & 1);   // round-to-nearest-even
    return (unsigned short)(u >> 16);
}

// ---- all 4 weights [K=256][N] fp32 -> Wt_all[2048][256] bf16 (transpose+convert)
// col map: 0..255 W_value | 256..1279 W_off | 1280..1791 W_attn | 1792..2047 W_out
__global__ __launch_bounds__(256) void convT_all(const float* __restrict__ Wv,
                                                 const float* __restrict__ Wo,
                                                 const float* __restrict__ Wa,
                                                 const float* __restrict__ Wu,
                                                 unsigned short* __restrict__ Wt) {
    __shared__ float tile[32][33];
    const int n0 = blockIdx.x * 32, k0 = blockIdx.y * 32;
    const float* src; int N, nloc;
    if (n0 < 256)       { src = Wv; N = 256;  nloc = n0; }
    else if (n0 < 1280) { src = Wo; N = 1024; nloc = n0 - 256; }
    else if (n0 < 1792) { src = Wa; N = 512;  nloc = n0 - 1280; }
    else                { src = Wu; N = 256;  nloc = n0 - 1792; }
    const int tx = threadIdx.x & 31, ty = threadIdx.x >> 5;  // ty 0..7
#pragma unroll
    for (int i = 0; i < 32; i += 8)
        tile[ty + i][tx] = src[(size_t)(k0 + ty + i) * N + nloc + tx];
    __syncthreads();
#pragma unroll
    for (int i = 0; i < 32; i += 8)
        Wt[(size_t)(n0 + ty + i) * KDIM + k0 + tx] = f2bf(tile[tx][ty + i]);
}

// ---------------- bf16 MFMA GEMM core, 128x128 tile (m97 structure) --------------
// 256 threads = 4 waves in 2x2; each wave computes 64x64 via 4x4 frags of
// 16x16x32. BK=32, K=256 fixed. A fp32 (converted in VGPRs during staging),
// B staged via global_load_lds width 16. Shared LDS passed in (one copy per
// kernel, not per template instantiation).
// MODE 1: fused qkv epilogue (N=1536): cols <1024 -> sampling locations with
//         reference-point polynomial (fp32 C); cols >=1024 -> attn logits with
//         fused softmax over the 64 logits of each (row, head) -> fp32 C2.
// MODE 2: bf16 C = f2bf(acc + bias[c])
template <int MODE>
__device__ __forceinline__ void gemm_core(short* As, short* Bs,
                                          const float* __restrict__ A,
                                          const unsigned short* __restrict__ Bt,
                                          const float* __restrict__ bias,
                                          const float* __restrict__ bias2,
                                          const float* __restrict__ refp,
                                          void* __restrict__ Cv,
                                          float* __restrict__ C2,
                                          int N, int bx, int by) {
    const int t = threadIdx.x;
    const int lane = t & 63, w = t >> 6;
    const int quad = lane >> 4, l16 = lane & 15;
    const int wr = w >> 1, wc = w & 1;
    const int row0 = by * 128, col0 = bx * 128;

    f32x4 acc[4][4] = {};

    // B staging: chunk covers 16B: row t>>2, k-offset (t&3)*8 elems
    const int bro = t >> 2, bko = (t & 3) * 8;
    const unsigned short* bsrc0 = Bt + (size_t)(col0 + bro) * KDIM + bko;
    const unsigned short* bsrc1 = bsrc0 + (size_t)64 * KDIM;
    short* const bdst0 = Bs + (size_t)(w * 64) * 8;          // + lane*16B by HW
    short* const bdst1 = Bs + (size_t)(256 + w * 64) * 8;

    // A staging (fp32): thread t covers 16 floats: row t>>1, k-half (t&1)*16
    const int ar = t >> 1, akq = (t & 1) * 16;
    const float* afsrc = A + (size_t)(row0 + ar) * KDIM + akq;
    short* const adst = As + ar * 32 + akq;

    for (int kt = 0; kt < KDIM / 32; ++kt) {
        __syncthreads();
        __builtin_amdgcn_global_load_lds(
            (const __attribute__((address_space(1))) void*)(bsrc0 + kt * 32),
            (__attribute__((address_space(3))) void*)bdst0, 16, 0, 0);
        __builtin_amdgcn_global_load_lds(
            (const __attribute__((address_space(1))) void*)(bsrc1 + kt * 32),
            (__attribute__((address_space(3))) void*)bdst1, 16, 0, 0);
        {
            const float* s = afsrc + kt * 32;
            const float4 f0 = *(const float4*)(s);
            const float4 f1 = *(const float4*)(s + 4);
            const float4 f2 = *(const float4*)(s + 8);
            const float4 f3 = *(const float4*)(s + 12);
            short8 h0, h1;
            h0[0] = (short)f2bf(f0.x); h0[1] = (short)f2bf(f0.y);
            h0[2] = (short)f2bf(f0.z); h0[3] = (short)f2bf(f0.w);
            h0[4] = (short)f2bf(f1.x); h0[5] = (short)f2bf(f1.y);
            h0[6] = (short)f2bf(f1.z); h0[7] = (short)f2bf(f1.w);
            h1[0] = (short)f2bf(f2.x); h1[1] = (short)f2bf(f2.y);
            h1[2] = (short)f2bf(f2.z); h1[3] = (short)f2bf(f2.w);
            h1[4] = (short)f2bf(f3.x); h1[5] = (short)f2bf(f3.y);
            h1[6] = (short)f2bf(f3.z); h1[7] = (short)f2bf(f3.w);
            *(short8*)(adst)     = h0;
            *(short8*)(adst + 8) = h1;
        }
        __syncthreads();

        short8 af[4], bf[4];
#pragma unroll
        for (int mi = 0; mi < 4; ++mi)
            af[mi] = *(const short8*)&As[(wr * 64 + mi * 16 + l16) * 32 + quad * 8];
#pragma unroll
        for (int ni = 0; ni < 4; ++ni)
            bf[ni] = *(const short8*)&Bs[(wc * 64 + ni * 16 + l16) * 32 + quad * 8];
#pragma unroll
        for (int mi = 0; mi < 4; ++mi)
#pragma unroll
            for (int ni = 0; ni < 4; ++ni)
                acc[mi][ni] = __builtin_amdgcn_mfma_f32_16x16x32_bf16(af[mi], bf[ni],
                                                                      acc[mi][ni], 0, 0, 0);
    }

    // C/D layout: col = lane&15, row = quad*4 + reg  [m89-verified, R2-R4 verified]
    if (MODE == 2) {
#pragma unroll
        for (int ni = 0; ni < 4; ++ni) {
            const int c = col0 + wc * 64 + ni * 16 + l16;
            const float bv = bias[c];
#pragma unroll
            for (int mi = 0; mi < 4; ++mi) {
                const int r0 = row0 + wr * 64 + mi * 16 + quad * 4;
#pragma unroll
                for (int rr = 0; rr < 4; ++rr)
                    ((unsigned short*)Cv)[(size_t)(r0 + rr) * N + c] =
                        f2bf(acc[mi][ni][rr] + bv);
            }
        }
    } else {
        const bool is_off = (col0 < 1024);   // block-uniform (1024 % 128 == 0)
        if (is_off) {
            float* C = (float*)Cv;
#pragma unroll
            for (int ni = 0; ni < 4; ++ni) {
                const int cg = col0 + wc * 64 + ni * 16 + l16;
                // cg = h*128 + l*32 + p*2 + xy
                const int xy = cg & 1, p = (cg >> 1) & 15, l = (cg >> 5) & 3;
                const float lam = (float)p * (1.0f / 15.0f);
                const float l2 = lam * lam, l3 = l2 * lam;
                const float rW = (l == 0) ? 0.015625f : (l == 1) ? 0.03125f
                                : (l == 2) ? 0.0625f : 0.125f;
                const float bv = bias[cg];
#pragma unroll
                for (int mi = 0; mi < 4; ++mi) {
                    const int r0 = row0 + wr * 64 + mi * 16 + quad * 4;
#pragma unroll
                    for (int rr = 0; rr < 4; ++rr) {
                        const int r = r0 + rr;
                        const float4 rp = *(const float4*)(refp + (size_t)r * 8 + xy * 4);
                        const float poly = rp.x * l3 + rp.y * l2 + rp.z * lam + rp.w;
                        C[(size_t)r * 1024 + cg] = poly + (acc[mi][ni][rr] + bv) * rW;
                    }
                }
            }
        } else {
            // fused softmax: this wave holds one head's 64 logits (ni*16+l16)
            // for 64 rows. Reduce over ni (in-reg) x l16 (shfl_xor 1,2,4,8).
            const int cabase = col0 - 1024 + wc * 64;   // multiple of 64
            float bv[4];
#pragma unroll
            for (int ni = 0; ni < 4; ++ni) bv[ni] = bias2[cabase + ni * 16 + l16];
#pragma unroll
            for (int mi = 0; mi < 4; ++mi) {
                const int r0 = row0 + wr * 64 + mi * 16 + quad * 4;
#pragma unroll
                for (int rr = 0; rr < 4; ++rr) {
                    float v0 = acc[mi][0][rr] + bv[0];
                    float v1 = acc[mi][1][rr] + bv[1];
                    float v2 = acc[mi][2][rr] + bv[2];
                    float v3 = acc[mi][3][rr] + bv[3];
                    float mx = fmaxf(fmaxf(v0, v1), fmaxf(v2, v3));
#pragma unroll
                    for (int mk = 1; mk < 16; mk <<= 1) mx = fmaxf(mx, __shfl_xor(mx, mk));
                    v0 = __expf(v0 - mx); v1 = __expf(v1 - mx);
                    v2 = __expf(v2 - mx); v3 = __expf(v3 - mx);
                    float s = v0 + v1 + v2 + v3;
#pragma unroll
                    for (int mk = 1; mk < 16; mk <<= 1) s += __shfl_xor(s, mk);
                    const float inv = 1.0f / s;
                    const size_t rb = (size_t)(r0 + rr) * 512 + cabase + l16;
                    C2[rb]      = v0 * inv;
                    C2[rb + 16] = v1 * inv;
                    C2[rb + 32] = v2 * inv;
                    C2[rb + 48] = v3 * inv;
                }
            }
        }
    }
}

// One launch covering both the v-projection (blocks 0..339) and the fused
// offsets+attn GEMM (blocks 340..723). Block-uniform role branch.
__global__ __launch_bounds__(256) void gemm_fused(const float* __restrict__ value,
                                                  const float* __restrict__ query,
                                                  const unsigned short* __restrict__ Wt,
                                                  const float* __restrict__ b_value,
                                                  const float* __restrict__ b_off,
                                                  const float* __restrict__ b_attn,
                                                  const float* __restrict__ refp,
                                                  unsigned short* __restrict__ v_proj,
                                                  float* __restrict__ loc_out,
                                                  float* __restrict__ attn_out) {
    __shared__ short As[128 * 32];
    __shared__ short Bs[128 * 32];
    const int b = blockIdx.x;
    if (b < 340) {
        gemm_core<2>(As, Bs, value, Wt, b_value, nullptr, nullptr,
                     v_proj, nullptr, 256, b & 1, b >> 1);
    } else {
        const int b2 = b - 340;
        gemm_core<1>(As, Bs, query, Wt + (size_t)256 * KDIM, b_off, b_attn, refp,
                     loc_out, attn_out, 1536, b2 % 12, b2 / 12);
    }
}

// ---------------- out-projection GEMM (A bf16 via glds), MODE-0 fp32 out ---------
__global__ __launch_bounds__(256) void gemm_out(const unsigned short* __restrict__ Abf,
                                                const unsigned short* __restrict__ Bt,
                                                const float* __restrict__ bias,
                                                float* __restrict__ C, int N) {
    __shared__ short As[128 * 32];
    __shared__ short Bs[128 * 32];
    const int t = threadIdx.x;
    const int lane = t & 63, w = t >> 6;
    const int quad = lane >> 4, l16 = lane & 15;
    const int wr = w >> 1, wc = w & 1;
    const int row0 = blockIdx.y * 128, col0 = blockIdx.x * 128;

    f32x4 acc[4][4] = {};

    const int bro = t >> 2, bko = (t & 3) * 8;
    const unsigned short* bsrc0 = Bt + (size_t)(col0 + bro) * KDIM + bko;
    const unsigned short* bsrc1 = bsrc0 + (size_t)64 * KDIM;
    short* const bdst0 = Bs + (size_t)(w * 64) * 8;
    short* const bdst1 = Bs + (size_t)(256 + w * 64) * 8;
    const unsigned short* absrc0 = Abf + (size_t)(row0 + bro) * KDIM + bko;
    const unsigned short* absrc1 = absrc0 + (size_t)64 * KDIM;
    short* const adst0 = As + (size_t)(w * 64) * 8;
    short* const adst1 = As + (size_t)(256 + w * 64) * 8;

    for (int kt = 0; kt < KDIM / 32; ++kt) {
        __syncthreads();
        __builtin_amdgcn_global_load_lds(
            (const __attribute__((address_space(1))) void*)(bsrc0 + kt * 32),
            (__attribute__((address_space(3))) void*)bdst0, 16, 0, 0);
        __builtin_amdgcn_global_load_lds(
            (const __attribute__((address_space(1))) void*)(bsrc1 + kt * 32),
            (__attribute__((address_space(3))) void*)bdst1, 16, 0, 0);
        __builtin_amdgcn_global_load_lds(
            (const __attribute__((address_space(1))) void*)(absrc0 + kt * 32),
            (__attribute__((address_space(3))) void*)adst0, 16, 0, 0);
        __builtin_amdgcn_global_load_lds(
            (const __attribute__((address_space(1))) void*)(absrc1 + kt * 32),
            (__attribute__((address_space(3))) void*)adst1, 16, 0, 0);
        __syncthreads();

        short8 af[4], bf[4];
#pragma unroll
        for (int mi = 0; mi < 4; ++mi)
            af[mi] = *(const short8*)&As[(wr * 64 + mi * 16 + l16) * 32 + quad * 8];
#pragma unroll
        for (int ni = 0; ni < 4; ++ni)
            bf[ni] = *(const short8*)&Bs[(wc * 64 + ni * 16 + l16) * 32 + quad * 8];
#pragma unroll
        for (int mi = 0; mi < 4; ++mi)
#pragma unroll
            for (int ni = 0; ni < 4; ++ni)
                acc[mi][ni] = __builtin_amdgcn_mfma_f32_16x16x32_bf16(af[mi], bf[ni],
                                                                      acc[mi][ni], 0, 0, 0);
    }
#pragma unroll
    for (int ni = 0; ni < 4; ++ni) {
        const int c = col0 + wc * 64 + ni * 16 + l16;
        const float bv = bias[c];
#pragma unroll
        for (int mi = 0; mi < 4; ++mi) {
            const int r0 = row0 + wr * 64 + mi * 16 + quad * 4;
#pragma unroll
            for (int rr = 0; rr < 4; ++rr)
                C[(size_t)(r0 + rr) * N + c] = acc[mi][ni][rr] + bv;
        }
    }
}

// ---------------- bilinear sampling + attention weighting (bf16 v) ---------------
// 16 lanes per (b,q,h): lane = (lvl 0..3) x (channel-octet 0..3); each lane
// loads 8 bf16 channels (16B) per corner -> 4 lanes cover a 64B head row.
// Scalar point math redundancy = 4x (vs 8x in R3). Cross-level reduce via
// shfl_xor(4,8). ANTI-SPILL (R4 lesson): the 16-point loop is NOT unrolled
// (4 points per iteration -> <=16 corner loads in flight) and launch_bounds
// pins VGPR <= 128.
__global__ __launch_bounds__(256, 4) void sample_kernel(const unsigned short* __restrict__ v,
                                                        const float* __restrict__ loc,
                                                        const float* __restrict__ attn,
                                                        unsigned short* __restrict__ interm) {
    const int t = threadIdx.x;
    const int g = blockIdx.x * 16 + (t >> 4);   // (b*1024+q)*8 + h
    const int l16i = t & 15;
    const int lvl = l16i >> 2;                  // level 0..3
    const int cq  = l16i & 3;                   // channel octet (8 bf16)
    const int h = g & 7, bq = g >> 3, b = bq >> 10;

    const int W = 64 >> lvl;
    const float Wf = (float)W;
    const int sh = 6 - lvl;
    const int start = (lvl == 0) ? 0 : (lvl == 1) ? 4096 : (lvl == 2) ? 5120 : 5376;

    const float* lp = loc  + (size_t)g * 128 + lvl * 32;   // this level's 16 pts
    const float* ap = attn + (size_t)g * 64  + lvl * 16;
    const unsigned short* vl = v + ((size_t)b * LV + start) * EMB + h * HD + cq * 8;

    float acc[8] = {};

    auto cadd = [&](const uint4 q, float wgt) {
        acc[0] = fmaf(wgt, __builtin_bit_cast(float, q.x << 16), acc[0]);
        acc[1] = fmaf(wgt, __builtin_bit_cast(float, q.x & 0xffff0000u), acc[1]);
        acc[2] = fmaf(wgt, __builtin_bit_cast(float, q.y << 16), acc[2]);
        acc[3] = fmaf(wgt, __builtin_bit_cast(float, q.y & 0xffff0000u), acc[3]);
        acc[4] = fmaf(wgt, __builtin_bit_cast(float, q.z << 16), acc[4]);
        acc[5] = fmaf(wgt, __builtin_bit_cast(float, q.z & 0xffff0000u), acc[5]);
        acc[6] = fmaf(wgt, __builtin_bit_cast(float, q.w << 16), acc[6]);
        acc[7] = fmaf(wgt, __builtin_bit_cast(float, q.w & 0xffff0000u), acc[7]);
    };

    auto point = [&](float lx, float ly, float wt) {
        const float x = lx * Wf - 0.5f, y = ly * Wf - 0.5f;
        const float x0f = floorf(x), y0f = floorf(y);
        const float wx = x - x0f, wy = y - y0f;
        const int x0 = (int)x0f, y0 = (int)y0f;
        const int x1 = x0 + 1, y1 = y0 + 1;
        const float iwx = 1.f - wx, iwy = 1.f - wy;
        float w00 = iwx * iwy * wt, w10 = wx * iwy * wt;
        float w01 = iwx * wy * wt,  w11 = wx * wy * wt;
        const bool vx0 = (unsigned)x0 < (unsigned)W;
        const bool vx1 = (unsigned)x1 < (unsigned)W;
        const bool vy0 = (unsigned)y0 < (unsigned)W;
        const bool vy1 = (unsigned)y1 < (unsigned)W;
        w00 = (vx0 & vy0) ? w00 : 0.f;
        w10 = (vx1 & vy0) ? w10 : 0.f;
        w01 = (vx0 & vy1) ? w01 : 0.f;
        w11 = (vx1 & vy1) ? w11 : 0.f;
        const int cx0 = min(max(x0, 0), W - 1);
        const int cx1 = min(max(x1, 0), W - 1);
        const int cy0 = min(max(y0, 0), W - 1);
        const int cy1 = min(max(y1, 0), W - 1);
        const uint4 g00 = *(const uint4*)(vl + (size_t)((cy0 << sh) + cx0) * EMB);
        const uint4 g10 = *(const uint4*)(vl + (size_t)((cy0 << sh) + cx1) * EMB);
        const uint4 g01 = *(const uint4*)(vl + (size_t)((cy1 << sh) + cx0) * EMB);
        const uint4 g11 = *(const uint4*)(vl + (size_t)((cy1 << sh) + cx1) * EMB);
        cadd(g00, w00); cadd(g10, w10); cadd(g01, w01); cadd(g11, w11);
    };

#pragma unroll 1
    for (int p4 = 0; p4 < 16; p4 += 4) {
        const float4 la = *(const float4*)(lp + 2 * p4);
        const float4 lb = *(const float4*)(lp + 2 * p4 + 4);
        const float4 wv = *(const float4*)(ap + p4);
        point(la.x, la.y, wv.x); point(la.z, la.w, wv.y);
        point(lb.x, lb.y, wv.z); point(lb.z, lb.w, wv.w);
    }

    // reduce across the 4 level-quads (lane bits 2,3)
#pragma unroll
    for (int m = 4; m <= 8; m <<= 1)
#pragma unroll
        for (int k = 0; k < 8; ++k) acc[k] += __shfl_xor(acc[k], m);

    if (lvl == 0) {
        unsigned short o[8];
#pragma unroll
        for (int k = 0; k < 8; ++k) o[k] = f2bf(acc[k]);
        *(uint4*)(interm + (size_t)bq * EMB + h * HD + cq * 8) = *(const uint4*)o;
    }
}

// ---------------- host launch ----------------------------------------------------
extern "C" void kernel_launch(void* const* d_in, const int* in_sizes, int n_in,
                              void* d_out, int out_size, void* d_ws, size_t ws_size,
                              hipStream_t stream) {
    const float* query   = (const float*)d_in[0];
    const float* refp    = (const float*)d_in[1];
    const float* value   = (const float*)d_in[2];
    const float* W_value = (const float*)d_in[3];
    const float* b_value = (const float*)d_in[4];
    const float* W_off   = (const float*)d_in[5];
    const float* b_off   = (const float*)d_in[6];
    const float* W_attn  = (const float*)d_in[7];
    const float* b_attn  = (const float*)d_in[8];
    const float* W_out   = (const float*)d_in[9];
    const float* b_out   = (const float*)d_in[10];

    float* out      = (float*)d_out;            // [4,1024,256]
    float* loc_out  = out + 1048576;            // [4,1024,8,4,16,2]
    float* attn_out = out + 5242880;            // [4,1024,8,4,16]

    // workspace layout (14,286,848 B)
    char* ws = (char*)d_ws;
    unsigned short* v_proj = (unsigned short*)ws;                 // 11,141,120 B (bf16)
    unsigned short* interm = (unsigned short*)(ws + 11141120);    //  2,097,152 B
    unsigned short* Wt_all = (unsigned short*)(ws + 13238272);    //  1,048,576 B

    const dim3 blk(256);

    // transpose+convert all weights -> Wt_all[2048][256] bf16
    convT_all<<<dim3(2048 / 32, 8), blk, 0, stream>>>(W_value, W_off, W_attn, W_out, Wt_all);

    // one launch: v-projection (340 blocks) + fused offsets/attn GEMM (384 blocks)
    gemm_fused<<<724, blk, 0, stream>>>(value, query, Wt_all, b_value, b_off, b_attn,
                                        refp, v_proj, loc_out, attn_out);

    // bilinear gather + attention weighting (bf16 v)
    sample_kernel<<<(BS * LQ * NH) / 16, blk, 0, stream>>>(v_proj, loc_out, attn_out, interm);

    // output = interm @ W_out + b  (A bf16, fp32 out)
    gemm_out<<<dim3(2, 32), blk, 0, stream>>>(interm, Wt_all + (size_t)1792 * KDIM,
                                              b_out, out, 256);
}